// Round 17
// baseline (51.164 us; speedup 1.0000x reference)
//
#include <hip/hip_runtime.h>

// Local windowed 2D autocorrelation.
// x: [8, 64, 128, 128] fp32; out: [8, 64, 31, 31, 8, 8] fp32.
// KH=KW=8, SH=SW=4, no padding.
//
// Round 17 = round 16 MINUS the LDS round-trip: each thread now owns its
// window's ENTIRE contiguous 256 B output block (one wave computes all 64
// offsets since round 15), so it stores its 16 result float4s directly.
// Round 5's 3.75x write amplification was NONTEMPORAL-specific (NT bypasses
// L2 -> partial-line fragments hit HBM); round 1's cached per-thread-256B
// stores showed no output amplification. Cached 16B stores merge in L2.
// Removes ~31 LDS instrs/thread + the 63.5 KB LDS residency cap.
// Tripwire: WRITE_SIZE must stay 123008 KB (inflation = L2 merge failure).
//
// Carried: one wave computes ALL 64 offsets (round 15: 5x TA-load cut,
// 42->32.8us); SROA-proof named f32x4/f32x2 SSA values only at kernel scope
// (rounds 13/14: kernel-scope arrays got PromoteAlloca'd into LDS+scratch);
// packed fp32 FMA (round 10: 61->42us); symmetry corr(dy,dx)=corr(-dy,-dx)
// (40 of 64 computed, mirrors via reversal + edge).

#define NH 31
#define NW 31

typedef float f32x4 __attribute__((ext_vector_type(4)));
typedef float f32x2 __attribute__((ext_vector_type(2)));

// One row-pair update for task D>=1: rows a (=row i) and b (=row i-D).
// P0..P3 = packed acc {ox=2p, 2p+1}; E = packed mirror-edge acc (if WE).
template <bool WE>
__device__ __forceinline__ void stepW(f32x4 al, f32x4 ah, f32x4 bl, f32x4 bh,
                                      f32x2& P0, f32x2& P1, f32x2& P2, f32x2& P3,
                                      f32x2& E) {
  float a[8] = {al.x, al.y, al.z, al.w, ah.x, ah.y, ah.z, ah.w};
  float b[8] = {bl.x, bl.y, bl.z, bl.w, bh.x, bh.y, bh.z, bh.w};
  f32x2 p0 = P0, p1 = P1, p2 = P2, p3 = P3;
#pragma unroll
  for (int j = 4; j <= 7; ++j) {  // pair p=0 (ox 0,1)
    f32x2 av = {a[j], a[j]};
    f32x2 bv = {b[j - 4], b[j - 3]};
    p0 = __builtin_elementwise_fma(av, bv, p0);
  }
#pragma unroll
  for (int j = 2; j <= 7; ++j) {  // pair p=1 (ox 2,3)
    f32x2 av = {a[j], a[j]};
    f32x2 bv = {b[j - 2], b[j - 1]};
    p1 = __builtin_elementwise_fma(av, bv, p1);
  }
#pragma unroll
  for (int j = 0; j <= 6; ++j) {  // pair p=2 (ox 4,5)
    f32x2 av = {a[j], a[j]};
    f32x2 bv = {b[j], b[j + 1]};
    p2 = __builtin_elementwise_fma(av, bv, p2);
  }
#pragma unroll
  for (int j = 0; j <= 4; ++j) {  // pair p=3 (ox 6,7)
    f32x2 av = {a[j], a[j]};
    f32x2 bv = {b[j + 2], b[j + 3]};
    p3 = __builtin_elementwise_fma(av, bv, p3);
  }
  p0.y = fmaf(a[3], b[0], p0.y);  // ox=1, j=3
  p1.y = fmaf(a[1], b[0], p1.y);  // ox=3, j=1
  p2.x = fmaf(a[7], b[7], p2.x);  // ox=4, j=7
  p3.x = fmaf(a[5], b[7], p3.x);  // ox=6, j=5
  if (WE) {
    f32x2 b0 = {b[4], b[5]}, a0 = {a[0], a[1]};
    f32x2 b1 = {b[6], b[7]}, a1 = {a[2], a[3]};
    E = __builtin_elementwise_fma(b0, a0, E);
    E = __builtin_elementwise_fma(b1, a1, E);
  }
  P0 = p0; P1 = p1; P2 = p2; P3 = p3;
}

// D=0 update for one row: only ox 0..4 (row 4 is self-mirrored).
__device__ __forceinline__ void step0(f32x4 al, f32x4 ah,
                                      f32x2& P0, f32x2& P1, f32x2& S) {
  float r[8] = {al.x, al.y, al.z, al.w, ah.x, ah.y, ah.z, ah.w};
  f32x2 p0 = P0, p1 = P1, s = S;
#pragma unroll
  for (int j = 4; j <= 7; ++j) {
    f32x2 av = {r[j], r[j]};
    f32x2 bv = {r[j - 4], r[j - 3]};
    p0 = __builtin_elementwise_fma(av, bv, p0);
  }
  p0.y = fmaf(r[3], r[0], p0.y);
#pragma unroll
  for (int j = 2; j <= 7; ++j) {
    f32x2 av = {r[j], r[j]};
    f32x2 bv = {r[j - 2], r[j - 1]};
    p1 = __builtin_elementwise_fma(av, bv, p1);
  }
  p1.y = fmaf(r[1], r[0], p1.y);
#pragma unroll
  for (int j = 0; j < 8; j += 2) {
    f32x2 v = {r[j], r[j + 1]};
    s = __builtin_elementwise_fma(v, v, s);
  }
  P0 = p0; P1 = p1; S = s;
}

__global__ __launch_bounds__(256, 1) void lacorr2d_kernel(
    const float* __restrict__ x, float* __restrict__ out) {
  const int g    = threadIdx.x >> 6;   // wave 0..3 -> hp-pair within quad
  const int lane = threadIdx.x & 63;
  const int w    = lane & 31;          // window col (31 = dead lane)
  const int hh   = lane >> 5;          // 0/1 within window-row pair

  const int q  = blockIdx.x & 3;       // hp quad
  const int bc = blockIdx.x >> 2;      // 0..511
  const int hp = q * 4 + g;            // window-row pair 0..15
  const int h  = hp * 2 + hh;          // 0..31 (31 invalid)
  const bool valid = (w < NW) && (h < NH);
  const int hc = valid ? h : 0;
  const int wc = valid ? w : 0;

  const float* src = x + (size_t)bc * (128 * 128) + (size_t)(hc * 4) * 128 + wc * 4;

  // 16 named row-half loads (no arrays -> nothing for PromoteAlloca).
  f32x4 rl0 = *(const f32x4*)(src + 0 * 128), rh0 = *(const f32x4*)(src + 0 * 128 + 4);
  f32x4 rl1 = *(const f32x4*)(src + 1 * 128), rh1 = *(const f32x4*)(src + 1 * 128 + 4);
  f32x4 rl2 = *(const f32x4*)(src + 2 * 128), rh2 = *(const f32x4*)(src + 2 * 128 + 4);
  f32x4 rl3 = *(const f32x4*)(src + 3 * 128), rh3 = *(const f32x4*)(src + 3 * 128 + 4);
  f32x4 rl4 = *(const f32x4*)(src + 4 * 128), rh4 = *(const f32x4*)(src + 4 * 128 + 4);
  f32x4 rl5 = *(const f32x4*)(src + 5 * 128), rh5 = *(const f32x4*)(src + 5 * 128 + 4);
  f32x4 rl6 = *(const f32x4*)(src + 6 * 128), rh6 = *(const f32x4*)(src + 6 * 128 + 4);
  f32x4 rl7 = *(const f32x4*)(src + 7 * 128), rh7 = *(const f32x4*)(src + 7 * 128 + 4);

  // Named packed accumulators (no arrays).
  f32x2 z = {0.f, 0.f};
  f32x2 d4p0 = z, d4p1 = z, d4p2 = z, d4p3 = z;
  f32x2 d3p0 = z, d3p1 = z, d3p2 = z, d3p3 = z, e3 = z;
  f32x2 d2p0 = z, d2p1 = z, d2p2 = z, d2p3 = z, e2 = z;
  f32x2 d1p0 = z, d1p1 = z, d1p2 = z, d1p3 = z, e1 = z;
  f32x2 d0p0 = z, d0p1 = z, s0 = z;
  f32x2 eDummy = z;

  // Single row sweep: at row i update D0(i,i), D1(i,i-1) ... D4(i,i-4).
  step0(rl0, rh0, d0p0, d0p1, s0);

  step0(rl1, rh1, d0p0, d0p1, s0);
  stepW<true>(rl1, rh1, rl0, rh0, d1p0, d1p1, d1p2, d1p3, e1);

  step0(rl2, rh2, d0p0, d0p1, s0);
  stepW<true>(rl2, rh2, rl1, rh1, d1p0, d1p1, d1p2, d1p3, e1);
  stepW<true>(rl2, rh2, rl0, rh0, d2p0, d2p1, d2p2, d2p3, e2);

  step0(rl3, rh3, d0p0, d0p1, s0);
  stepW<true>(rl3, rh3, rl2, rh2, d1p0, d1p1, d1p2, d1p3, e1);
  stepW<true>(rl3, rh3, rl1, rh1, d2p0, d2p1, d2p2, d2p3, e2);
  stepW<true>(rl3, rh3, rl0, rh0, d3p0, d3p1, d3p2, d3p3, e3);

  step0(rl4, rh4, d0p0, d0p1, s0);
  stepW<true>(rl4, rh4, rl3, rh3, d1p0, d1p1, d1p2, d1p3, e1);
  stepW<true>(rl4, rh4, rl2, rh2, d2p0, d2p1, d2p2, d2p3, e2);
  stepW<true>(rl4, rh4, rl1, rh1, d3p0, d3p1, d3p2, d3p3, e3);
  stepW<false>(rl4, rh4, rl0, rh0, d4p0, d4p1, d4p2, d4p3, eDummy);

  step0(rl5, rh5, d0p0, d0p1, s0);
  stepW<true>(rl5, rh5, rl4, rh4, d1p0, d1p1, d1p2, d1p3, e1);
  stepW<true>(rl5, rh5, rl3, rh3, d2p0, d2p1, d2p2, d2p3, e2);
  stepW<true>(rl5, rh5, rl2, rh2, d3p0, d3p1, d3p2, d3p3, e3);
  stepW<false>(rl5, rh5, rl1, rh1, d4p0, d4p1, d4p2, d4p3, eDummy);

  step0(rl6, rh6, d0p0, d0p1, s0);
  stepW<true>(rl6, rh6, rl5, rh5, d1p0, d1p1, d1p2, d1p3, e1);
  stepW<true>(rl6, rh6, rl4, rh4, d2p0, d2p1, d2p2, d2p3, e2);
  stepW<true>(rl6, rh6, rl3, rh3, d3p0, d3p1, d3p2, d3p3, e3);
  stepW<false>(rl6, rh6, rl2, rh2, d4p0, d4p1, d4p2, d4p3, eDummy);

  step0(rl7, rh7, d0p0, d0p1, s0);
  stepW<true>(rl7, rh7, rl6, rh6, d1p0, d1p1, d1p2, d1p3, e1);
  stepW<true>(rl7, rh7, rl5, rh5, d2p0, d2p1, d2p2, d2p3, e2);
  stepW<true>(rl7, rh7, rl4, rh4, d3p0, d3p1, d3p2, d3p3, e3);
  stepW<false>(rl7, rh7, rl3, rh3, d4p0, d4p1, d4p2, d4p3, eDummy);

  const float ev1 = e1.x + e1.y;
  const float ev2 = e2.x + e2.y;
  const float ev3 = e3.x + e3.y;
  const float a4  = s0.x + s0.y;

  if (valid) {
    // This thread owns the whole 256 B output block of its window.
    float* dst = out + ((size_t)(bc * NH + hc) * NW + wc) * 64;
#define ST4(off, A, B, C, Dv)                                               \
  do {                                                                      \
    f32x4 v_ = {A, B, C, Dv};                                               \
    *reinterpret_cast<f32x4*>(dst + (off)) = v_;                            \
  } while (0)
    // row 0 (oy=0, dy=-4)
    ST4(0,  d4p0.x, d4p0.y, d4p1.x, d4p1.y);
    ST4(4,  d4p2.x, d4p2.y, d4p3.x, d4p3.y);
    // row 1 (dy=-3)
    ST4(8,  d3p0.x, d3p0.y, d3p1.x, d3p1.y);
    ST4(12, d3p2.x, d3p2.y, d3p3.x, d3p3.y);
    // row 2 (dy=-2)
    ST4(16, d2p0.x, d2p0.y, d2p1.x, d2p1.y);
    ST4(20, d2p2.x, d2p2.y, d2p3.x, d2p3.y);
    // row 3 (dy=-1)
    ST4(24, d1p0.x, d1p0.y, d1p1.x, d1p1.y);
    ST4(28, d1p2.x, d1p2.y, d1p3.x, d1p3.y);
    // row 4 (dy=0, self-mirrored)
    ST4(32, d0p0.x, d0p0.y, d0p1.x, d0p1.y);
    ST4(36, a4,     d0p1.y, d0p1.x, d0p0.y);
    // row 5 = mirror of row 3
    ST4(40, ev1,    d1p3.y, d1p3.x, d1p2.y);
    ST4(44, d1p2.x, d1p1.y, d1p1.x, d1p0.y);
    // row 6 = mirror of row 2
    ST4(48, ev2,    d2p3.y, d2p3.x, d2p2.y);
    ST4(52, d2p2.x, d2p1.y, d2p1.x, d2p0.y);
    // row 7 = mirror of row 1
    ST4(56, ev3,    d3p3.y, d3p3.x, d3p2.y);
    ST4(60, d3p2.x, d3p1.y, d3p1.x, d3p0.y);
#undef ST4
  }
}

extern "C" void kernel_launch(void* const* d_in, const int* in_sizes, int n_in,
                              void* d_out, int out_size, void* d_ws, size_t ws_size,
                              hipStream_t stream) {
  const float* x = (const float*)d_in[0];
  float* out = (float*)d_out;
  // 512 bc-planes x 4 hp-quads
  lacorr2d_kernel<<<512 * 4, 256, 0, stream>>>(x, out);
}

// Round 18
// 33.767 us; speedup vs baseline: 1.5152x; 1.5152x over previous
//
#include <hip/hip_runtime.h>

// Local windowed 2D autocorrelation.
// x: [8, 64, 128, 128] fp32; out: [8, 64, 31, 31, 8, 8] fp32.
// KH=KW=8, SH=SW=4, no padding.
//
// Round 18 = round 16 (32.3us, session best) with HALF-PLANE LDS staging:
// each wave now uses ONE 7.9KB plane twice (phase A: hh=0 lanes' row, drain;
// phase B: hh=1 lanes' row into the same plane, drain). Same-wave DS ops are
// hardware-in-order -> no barrier needed; planes are wave-private.
// LDS/block 63.5KB -> 31.75KB => residency 2 -> 4-5 blocks/CU. Theory: with
// 2 lockstep blocks/CU the compute phase leaves HBM idle and the drain phase
// leaves VALU idle (4 generations of burst); more phase-staggered blocks
// interleave the two. Round 17 lesson (direct stores, 51us): scattered
// 256B-stride stores throttle on L2 transaction rate -- LDS assembly +
// lane-consecutive full-line copy-out is load-bearing.
//
// Carried: one wave computes ALL 64 offsets (round 15: 5x TA-load cut);
// SROA-proof named f32x4/f32x2 SSA values only at kernel scope (rounds
// 13/14: kernel-scope arrays got PromoteAlloca'd into LDS+scratch); packed
// fp32 FMA (round 10: 61->42us); symmetry corr(dy,dx)=corr(-dy,-dx) (40 of
// 64 computed); XOR-swizzle (w&7) = conflict-free LDS.
// Tripwires: LDS_Block_Size ~31744, WRITE_SIZE 123008 KB, conflicts ~0.

#define NH 31
#define NW 31

typedef float f32x4 __attribute__((ext_vector_type(4)));
typedef float f32x2 __attribute__((ext_vector_type(2)));

// One row-pair update for task D>=1: rows a (=row i) and b (=row i-D).
// P0..P3 = packed acc {ox=2p, 2p+1}; E = packed mirror-edge acc (if WE).
template <bool WE>
__device__ __forceinline__ void stepW(f32x4 al, f32x4 ah, f32x4 bl, f32x4 bh,
                                      f32x2& P0, f32x2& P1, f32x2& P2, f32x2& P3,
                                      f32x2& E) {
  float a[8] = {al.x, al.y, al.z, al.w, ah.x, ah.y, ah.z, ah.w};
  float b[8] = {bl.x, bl.y, bl.z, bl.w, bh.x, bh.y, bh.z, bh.w};
  f32x2 p0 = P0, p1 = P1, p2 = P2, p3 = P3;
#pragma unroll
  for (int j = 4; j <= 7; ++j) {  // pair p=0 (ox 0,1)
    f32x2 av = {a[j], a[j]};
    f32x2 bv = {b[j - 4], b[j - 3]};
    p0 = __builtin_elementwise_fma(av, bv, p0);
  }
#pragma unroll
  for (int j = 2; j <= 7; ++j) {  // pair p=1 (ox 2,3)
    f32x2 av = {a[j], a[j]};
    f32x2 bv = {b[j - 2], b[j - 1]};
    p1 = __builtin_elementwise_fma(av, bv, p1);
  }
#pragma unroll
  for (int j = 0; j <= 6; ++j) {  // pair p=2 (ox 4,5)
    f32x2 av = {a[j], a[j]};
    f32x2 bv = {b[j], b[j + 1]};
    p2 = __builtin_elementwise_fma(av, bv, p2);
  }
#pragma unroll
  for (int j = 0; j <= 4; ++j) {  // pair p=3 (ox 6,7)
    f32x2 av = {a[j], a[j]};
    f32x2 bv = {b[j + 2], b[j + 3]};
    p3 = __builtin_elementwise_fma(av, bv, p3);
  }
  p0.y = fmaf(a[3], b[0], p0.y);  // ox=1, j=3
  p1.y = fmaf(a[1], b[0], p1.y);  // ox=3, j=1
  p2.x = fmaf(a[7], b[7], p2.x);  // ox=4, j=7
  p3.x = fmaf(a[5], b[7], p3.x);  // ox=6, j=5
  if (WE) {
    f32x2 b0 = {b[4], b[5]}, a0 = {a[0], a[1]};
    f32x2 b1 = {b[6], b[7]}, a1 = {a[2], a[3]};
    E = __builtin_elementwise_fma(b0, a0, E);
    E = __builtin_elementwise_fma(b1, a1, E);
  }
  P0 = p0; P1 = p1; P2 = p2; P3 = p3;
}

// D=0 update for one row: only ox 0..4 (row 4 is self-mirrored).
__device__ __forceinline__ void step0(f32x4 al, f32x4 ah,
                                      f32x2& P0, f32x2& P1, f32x2& S) {
  float r[8] = {al.x, al.y, al.z, al.w, ah.x, ah.y, ah.z, ah.w};
  f32x2 p0 = P0, p1 = P1, s = S;
#pragma unroll
  for (int j = 4; j <= 7; ++j) {
    f32x2 av = {r[j], r[j]};
    f32x2 bv = {r[j - 4], r[j - 3]};
    p0 = __builtin_elementwise_fma(av, bv, p0);
  }
  p0.y = fmaf(r[3], r[0], p0.y);
#pragma unroll
  for (int j = 2; j <= 7; ++j) {
    f32x2 av = {r[j], r[j]};
    f32x2 bv = {r[j - 2], r[j - 1]};
    p1 = __builtin_elementwise_fma(av, bv, p1);
  }
  p1.y = fmaf(r[1], r[0], p1.y);
#pragma unroll
  for (int j = 0; j < 8; j += 2) {
    f32x2 v = {r[j], r[j + 1]};
    s = __builtin_elementwise_fma(v, v, s);
  }
  P0 = p0; P1 = p1; S = s;
}

__global__ __launch_bounds__(256, 1) void lacorr2d_kernel(
    const float* __restrict__ x, float* __restrict__ out) {
  __shared__ __align__(16) float lds[4][31][64];  // 31.75 KB, 1 plane/wave

  const int g    = threadIdx.x >> 6;   // wave 0..3 -> hp-pair within quad
  const int lane = threadIdx.x & 63;
  const int w    = lane & 31;          // window col (31 = dead lane)
  const int hh   = lane >> 5;          // 0/1 within window-row pair

  const int q  = blockIdx.x & 3;       // hp quad
  const int bc = blockIdx.x >> 2;      // 0..511
  const int hp = q * 4 + g;            // window-row pair 0..15
  const int h  = hp * 2 + hh;          // 0..31 (31 invalid)
  const bool valid = (w < NW) && (h < NH);
  const int hc = valid ? h : 0;
  const int wc = valid ? w : 0;

  const float* src = x + (size_t)bc * (128 * 128) + (size_t)(hc * 4) * 128 + wc * 4;
  float* wbase = &lds[g][wc][0];
  const int sw = wc & 7;  // swizzle key

  // 16 named row-half loads (no arrays -> nothing for PromoteAlloca).
  f32x4 rl0 = *(const f32x4*)(src + 0 * 128), rh0 = *(const f32x4*)(src + 0 * 128 + 4);
  f32x4 rl1 = *(const f32x4*)(src + 1 * 128), rh1 = *(const f32x4*)(src + 1 * 128 + 4);
  f32x4 rl2 = *(const f32x4*)(src + 2 * 128), rh2 = *(const f32x4*)(src + 2 * 128 + 4);
  f32x4 rl3 = *(const f32x4*)(src + 3 * 128), rh3 = *(const f32x4*)(src + 3 * 128 + 4);
  f32x4 rl4 = *(const f32x4*)(src + 4 * 128), rh4 = *(const f32x4*)(src + 4 * 128 + 4);
  f32x4 rl5 = *(const f32x4*)(src + 5 * 128), rh5 = *(const f32x4*)(src + 5 * 128 + 4);
  f32x4 rl6 = *(const f32x4*)(src + 6 * 128), rh6 = *(const f32x4*)(src + 6 * 128 + 4);
  f32x4 rl7 = *(const f32x4*)(src + 7 * 128), rh7 = *(const f32x4*)(src + 7 * 128 + 4);

  // Named packed accumulators (no arrays).
  f32x2 z = {0.f, 0.f};
  f32x2 d4p0 = z, d4p1 = z, d4p2 = z, d4p3 = z;
  f32x2 d3p0 = z, d3p1 = z, d3p2 = z, d3p3 = z, e3 = z;
  f32x2 d2p0 = z, d2p1 = z, d2p2 = z, d2p3 = z, e2 = z;
  f32x2 d1p0 = z, d1p1 = z, d1p2 = z, d1p3 = z, e1 = z;
  f32x2 d0p0 = z, d0p1 = z, s0 = z;
  f32x2 eDummy = z;

  // Single row sweep: at row i update D0(i,i), D1(i,i-1) ... D4(i,i-4).
  step0(rl0, rh0, d0p0, d0p1, s0);

  step0(rl1, rh1, d0p0, d0p1, s0);
  stepW<true>(rl1, rh1, rl0, rh0, d1p0, d1p1, d1p2, d1p3, e1);

  step0(rl2, rh2, d0p0, d0p1, s0);
  stepW<true>(rl2, rh2, rl1, rh1, d1p0, d1p1, d1p2, d1p3, e1);
  stepW<true>(rl2, rh2, rl0, rh0, d2p0, d2p1, d2p2, d2p3, e2);

  step0(rl3, rh3, d0p0, d0p1, s0);
  stepW<true>(rl3, rh3, rl2, rh2, d1p0, d1p1, d1p2, d1p3, e1);
  stepW<true>(rl3, rh3, rl1, rh1, d2p0, d2p1, d2p2, d2p3, e2);
  stepW<true>(rl3, rh3, rl0, rh0, d3p0, d3p1, d3p2, d3p3, e3);

  step0(rl4, rh4, d0p0, d0p1, s0);
  stepW<true>(rl4, rh4, rl3, rh3, d1p0, d1p1, d1p2, d1p3, e1);
  stepW<true>(rl4, rh4, rl2, rh2, d2p0, d2p1, d2p2, d2p3, e2);
  stepW<true>(rl4, rh4, rl1, rh1, d3p0, d3p1, d3p2, d3p3, e3);
  stepW<false>(rl4, rh4, rl0, rh0, d4p0, d4p1, d4p2, d4p3, eDummy);

  step0(rl5, rh5, d0p0, d0p1, s0);
  stepW<true>(rl5, rh5, rl4, rh4, d1p0, d1p1, d1p2, d1p3, e1);
  stepW<true>(rl5, rh5, rl3, rh3, d2p0, d2p1, d2p2, d2p3, e2);
  stepW<true>(rl5, rh5, rl2, rh2, d3p0, d3p1, d3p2, d3p3, e3);
  stepW<false>(rl5, rh5, rl1, rh1, d4p0, d4p1, d4p2, d4p3, eDummy);

  step0(rl6, rh6, d0p0, d0p1, s0);
  stepW<true>(rl6, rh6, rl5, rh5, d1p0, d1p1, d1p2, d1p3, e1);
  stepW<true>(rl6, rh6, rl4, rh4, d2p0, d2p1, d2p2, d2p3, e2);
  stepW<true>(rl6, rh6, rl3, rh3, d3p0, d3p1, d3p2, d3p3, e3);
  stepW<false>(rl6, rh6, rl2, rh2, d4p0, d4p1, d4p2, d4p3, eDummy);

  step0(rl7, rh7, d0p0, d0p1, s0);
  stepW<true>(rl7, rh7, rl6, rh6, d1p0, d1p1, d1p2, d1p3, e1);
  stepW<true>(rl7, rh7, rl5, rh5, d2p0, d2p1, d2p2, d2p3, e2);
  stepW<true>(rl7, rh7, rl4, rh4, d3p0, d3p1, d3p2, d3p3, e3);
  stepW<false>(rl7, rh7, rl3, rh3, d4p0, d4p1, d4p2, d4p3, eDummy);

  const float ev1 = e1.x + e1.y;
  const float ev2 = e2.x + e2.y;
  const float ev3 = e3.x + e3.y;
  const float a4  = s0.x + s0.y;

#define LDS_ST(e4, A, B, C, Dv)                                             \
  do {                                                                      \
    f32x4 v_ = {A, B, C, Dv};                                               \
    *reinterpret_cast<f32x4*>(wbase + (((e4) ^ sw) << 2)) = v_;             \
  } while (0)
#define STORE_ALL16()                                                       \
  do {                                                                      \
    LDS_ST(0,  d4p0.x, d4p0.y, d4p1.x, d4p1.y);                             \
    LDS_ST(1,  d4p2.x, d4p2.y, d4p3.x, d4p3.y);                             \
    LDS_ST(2,  d3p0.x, d3p0.y, d3p1.x, d3p1.y);                             \
    LDS_ST(3,  d3p2.x, d3p2.y, d3p3.x, d3p3.y);                             \
    LDS_ST(14, ev3,    d3p3.y, d3p3.x, d3p2.y);                             \
    LDS_ST(15, d3p2.x, d3p1.y, d3p1.x, d3p0.y);                             \
    LDS_ST(4,  d2p0.x, d2p0.y, d2p1.x, d2p1.y);                             \
    LDS_ST(5,  d2p2.x, d2p2.y, d2p3.x, d2p3.y);                             \
    LDS_ST(12, ev2,    d2p3.y, d2p3.x, d2p2.y);                             \
    LDS_ST(13, d2p2.x, d2p1.y, d2p1.x, d2p0.y);                             \
    LDS_ST(6,  d1p0.x, d1p0.y, d1p1.x, d1p1.y);                             \
    LDS_ST(7,  d1p2.x, d1p2.y, d1p3.x, d1p3.y);                             \
    LDS_ST(10, ev1,    d1p3.y, d1p3.x, d1p2.y);                             \
    LDS_ST(11, d1p2.x, d1p1.y, d1p1.x, d1p0.y);                             \
    LDS_ST(8,  d0p0.x, d0p0.y, d0p1.x, d0p1.y);                             \
    LDS_ST(9,  a4,     d0p1.y, d0p1.x, d0p0.y);                             \
  } while (0)

  // Phase A: hh=0 lanes stage their row (h = 2hp, always < NH), wave drains.
  if (valid && hh == 0) STORE_ALL16();
  {
    float* orun = out + (size_t)(bc * NH + hp * 2) * (NW * 64);
    for (int idx = lane; idx < NW * 16; idx += 64) {
      const int ww = idx >> 4;
      const int e4 = idx & 15;
      f32x4 v = *reinterpret_cast<const f32x4*>(&lds[g][ww][(e4 ^ (ww & 7)) << 2]);
      *reinterpret_cast<f32x4*>(orun + (size_t)idx * 4) = v;
    }
  }

  // Phase B: hh=1 lanes stage their row (h = 2hp+1) into the SAME plane,
  // wave drains. Same-wave DS ops are in-order; plane is wave-private.
  if (valid && hh == 1) STORE_ALL16();
  if (hp * 2 + 1 < NH) {  // wave-uniform (false only for hp=15)
    float* orun = out + (size_t)(bc * NH + hp * 2 + 1) * (NW * 64);
    for (int idx = lane; idx < NW * 16; idx += 64) {
      const int ww = idx >> 4;
      const int e4 = idx & 15;
      f32x4 v = *reinterpret_cast<const f32x4*>(&lds[g][ww][(e4 ^ (ww & 7)) << 2]);
      *reinterpret_cast<f32x4*>(orun + (size_t)idx * 4) = v;
    }
  }
#undef STORE_ALL16
#undef LDS_ST
}

extern "C" void kernel_launch(void* const* d_in, const int* in_sizes, int n_in,
                              void* d_out, int out_size, void* d_ws, size_t ws_size,
                              hipStream_t stream) {
  const float* x = (const float*)d_in[0];
  float* out = (float*)d_out;
  // 512 bc-planes x 4 hp-quads
  lacorr2d_kernel<<<512 * 4, 256, 0, stream>>>(x, out);
}

// Round 19
// 32.376 us; speedup vs baseline: 1.5803x; 1.0430x over previous
//
#include <hip/hip_runtime.h>

// Local windowed 2D autocorrelation.
// x: [8, 64, 128, 128] fp32; out: [8, 64, 31, 31, 8, 8] fp32.
// KH=KW=8, SH=SW=4, no padding.
//
// FINAL (round 19) = round 16 verbatim, the session best (32.3us).
// Round 18's half-plane staging (more blocks/CU) regressed to 33.8 ->
// reverted. Plateau analysis: VALU issue bound ~20us (744 wave-ops/thread,
// 1.86 MAC/slot packing of 2.0 ideal, symmetry-halved), memory bound ~21us
// (147MB at the 7TB/s the harness fill kernel demonstrates); measured 32.3
// sits between perfect-overlap (21) and zero-overlap (41) with both pipes
// ~65% busy. Five structural levers (persistent blocks x2, fat blocks,
// prefetch, LDS halving) all null/negative -> practical roofline.
//
// Structure:
//  - 8192 one-shot blocks of 4 waves; wave = one hp-pair (62 windows).
//  - One wave computes ALL 64 offsets of its windows (round 15: 5x TA-load
//    cut, 42->32.8us). SROA-proof: ONLY named f32x4/f32x2 SSA values at
//    kernel scope (rounds 13/14: kernel-scope arrays got PromoteAlloca'd
//    into LDS+scratch: +18KB LDS, 3.2M bank conflicts, +49MB spill writes).
//  - Packed fp32 FMA via f32x2 + __builtin_elementwise_fma -> v_pk_fma_f32
//    (round 10: 61->42us).
//  - Symmetry corr(dy,dx)=corr(-dy,-dx): 40 of 64 values computed; rows 5-7
//    are reversals of rows 3-1 plus one edge value each.
//  - Results assembled in wave-private LDS planes, streamed out as
//    contiguous full-line float4 runs (round 5: scattered 32B stores =
//    3.75x HBM write amplification; round 17: direct 256B-stride stores =
//    L2 transaction throttle, 51us). XOR-swizzle (w&7) = conflict-free.
//  - No __syncthreads: waves touch only their own LDS planes; same-wave
//    DS ordering is hardware-enforced (round 16: -0.5us vs barrier).

#define NH 31
#define NW 31

typedef float f32x4 __attribute__((ext_vector_type(4)));
typedef float f32x2 __attribute__((ext_vector_type(2)));

// One row-pair update for task D>=1: rows a (=row i) and b (=row i-D).
// P0..P3 = packed acc {ox=2p, 2p+1}; E = packed mirror-edge acc (if WE).
template <bool WE>
__device__ __forceinline__ void stepW(f32x4 al, f32x4 ah, f32x4 bl, f32x4 bh,
                                      f32x2& P0, f32x2& P1, f32x2& P2, f32x2& P3,
                                      f32x2& E) {
  float a[8] = {al.x, al.y, al.z, al.w, ah.x, ah.y, ah.z, ah.w};
  float b[8] = {bl.x, bl.y, bl.z, bl.w, bh.x, bh.y, bh.z, bh.w};
  f32x2 p0 = P0, p1 = P1, p2 = P2, p3 = P3;
#pragma unroll
  for (int j = 4; j <= 7; ++j) {  // pair p=0 (ox 0,1)
    f32x2 av = {a[j], a[j]};
    f32x2 bv = {b[j - 4], b[j - 3]};
    p0 = __builtin_elementwise_fma(av, bv, p0);
  }
#pragma unroll
  for (int j = 2; j <= 7; ++j) {  // pair p=1 (ox 2,3)
    f32x2 av = {a[j], a[j]};
    f32x2 bv = {b[j - 2], b[j - 1]};
    p1 = __builtin_elementwise_fma(av, bv, p1);
  }
#pragma unroll
  for (int j = 0; j <= 6; ++j) {  // pair p=2 (ox 4,5)
    f32x2 av = {a[j], a[j]};
    f32x2 bv = {b[j], b[j + 1]};
    p2 = __builtin_elementwise_fma(av, bv, p2);
  }
#pragma unroll
  for (int j = 0; j <= 4; ++j) {  // pair p=3 (ox 6,7)
    f32x2 av = {a[j], a[j]};
    f32x2 bv = {b[j + 2], b[j + 3]};
    p3 = __builtin_elementwise_fma(av, bv, p3);
  }
  p0.y = fmaf(a[3], b[0], p0.y);  // ox=1, j=3
  p1.y = fmaf(a[1], b[0], p1.y);  // ox=3, j=1
  p2.x = fmaf(a[7], b[7], p2.x);  // ox=4, j=7
  p3.x = fmaf(a[5], b[7], p3.x);  // ox=6, j=5
  if (WE) {
    f32x2 b0 = {b[4], b[5]}, a0 = {a[0], a[1]};
    f32x2 b1 = {b[6], b[7]}, a1 = {a[2], a[3]};
    E = __builtin_elementwise_fma(b0, a0, E);
    E = __builtin_elementwise_fma(b1, a1, E);
  }
  P0 = p0; P1 = p1; P2 = p2; P3 = p3;
}

// D=0 update for one row: only ox 0..4 (row 4 is self-mirrored).
__device__ __forceinline__ void step0(f32x4 al, f32x4 ah,
                                      f32x2& P0, f32x2& P1, f32x2& S) {
  float r[8] = {al.x, al.y, al.z, al.w, ah.x, ah.y, ah.z, ah.w};
  f32x2 p0 = P0, p1 = P1, s = S;
#pragma unroll
  for (int j = 4; j <= 7; ++j) {
    f32x2 av = {r[j], r[j]};
    f32x2 bv = {r[j - 4], r[j - 3]};
    p0 = __builtin_elementwise_fma(av, bv, p0);
  }
  p0.y = fmaf(r[3], r[0], p0.y);
#pragma unroll
  for (int j = 2; j <= 7; ++j) {
    f32x2 av = {r[j], r[j]};
    f32x2 bv = {r[j - 2], r[j - 1]};
    p1 = __builtin_elementwise_fma(av, bv, p1);
  }
  p1.y = fmaf(r[1], r[0], p1.y);
#pragma unroll
  for (int j = 0; j < 8; j += 2) {
    f32x2 v = {r[j], r[j + 1]};
    s = __builtin_elementwise_fma(v, v, s);
  }
  P0 = p0; P1 = p1; S = s;
}

__global__ __launch_bounds__(256, 1) void lacorr2d_kernel(
    const float* __restrict__ x, float* __restrict__ out) {
  __shared__ __align__(16) float lds[8][31][64];  // 63.5 KB, 2 planes/wave

  const int g    = threadIdx.x >> 6;   // wave 0..3 -> hp-pair within quad
  const int lane = threadIdx.x & 63;
  const int w    = lane & 31;          // window col (31 = dead lane)
  const int hh   = lane >> 5;          // 0/1 within window-row pair

  const int q  = blockIdx.x & 3;       // hp quad
  const int bc = blockIdx.x >> 2;      // 0..511
  const int hp = q * 4 + g;            // window-row pair 0..15
  const int h  = hp * 2 + hh;          // 0..31 (31 invalid)
  const bool valid = (w < NW) && (h < NH);
  const int hc = valid ? h : 0;
  const int wc = valid ? w : 0;

  const float* src = x + (size_t)bc * (128 * 128) + (size_t)(hc * 4) * 128 + wc * 4;
  float* wbase = &lds[2 * g + hh][wc][0];
  const int sw = wc & 7;  // swizzle key

  // 16 named row-half loads (no arrays -> nothing for PromoteAlloca).
  f32x4 rl0 = *(const f32x4*)(src + 0 * 128), rh0 = *(const f32x4*)(src + 0 * 128 + 4);
  f32x4 rl1 = *(const f32x4*)(src + 1 * 128), rh1 = *(const f32x4*)(src + 1 * 128 + 4);
  f32x4 rl2 = *(const f32x4*)(src + 2 * 128), rh2 = *(const f32x4*)(src + 2 * 128 + 4);
  f32x4 rl3 = *(const f32x4*)(src + 3 * 128), rh3 = *(const f32x4*)(src + 3 * 128 + 4);
  f32x4 rl4 = *(const f32x4*)(src + 4 * 128), rh4 = *(const f32x4*)(src + 4 * 128 + 4);
  f32x4 rl5 = *(const f32x4*)(src + 5 * 128), rh5 = *(const f32x4*)(src + 5 * 128 + 4);
  f32x4 rl6 = *(const f32x4*)(src + 6 * 128), rh6 = *(const f32x4*)(src + 6 * 128 + 4);
  f32x4 rl7 = *(const f32x4*)(src + 7 * 128), rh7 = *(const f32x4*)(src + 7 * 128 + 4);

  // Named packed accumulators (no arrays).
  f32x2 z = {0.f, 0.f};
  f32x2 d4p0 = z, d4p1 = z, d4p2 = z, d4p3 = z;
  f32x2 d3p0 = z, d3p1 = z, d3p2 = z, d3p3 = z, e3 = z;
  f32x2 d2p0 = z, d2p1 = z, d2p2 = z, d2p3 = z, e2 = z;
  f32x2 d1p0 = z, d1p1 = z, d1p2 = z, d1p3 = z, e1 = z;
  f32x2 d0p0 = z, d0p1 = z, s0 = z;
  f32x2 eDummy = z;

  // Single row sweep: at row i update D0(i,i), D1(i,i-1) ... D4(i,i-4).
  step0(rl0, rh0, d0p0, d0p1, s0);

  step0(rl1, rh1, d0p0, d0p1, s0);
  stepW<true>(rl1, rh1, rl0, rh0, d1p0, d1p1, d1p2, d1p3, e1);

  step0(rl2, rh2, d0p0, d0p1, s0);
  stepW<true>(rl2, rh2, rl1, rh1, d1p0, d1p1, d1p2, d1p3, e1);
  stepW<true>(rl2, rh2, rl0, rh0, d2p0, d2p1, d2p2, d2p3, e2);

  step0(rl3, rh3, d0p0, d0p1, s0);
  stepW<true>(rl3, rh3, rl2, rh2, d1p0, d1p1, d1p2, d1p3, e1);
  stepW<true>(rl3, rh3, rl1, rh1, d2p0, d2p1, d2p2, d2p3, e2);
  stepW<true>(rl3, rh3, rl0, rh0, d3p0, d3p1, d3p2, d3p3, e3);

  step0(rl4, rh4, d0p0, d0p1, s0);
  stepW<true>(rl4, rh4, rl3, rh3, d1p0, d1p1, d1p2, d1p3, e1);
  stepW<true>(rl4, rh4, rl2, rh2, d2p0, d2p1, d2p2, d2p3, e2);
  stepW<true>(rl4, rh4, rl1, rh1, d3p0, d3p1, d3p2, d3p3, e3);
  stepW<false>(rl4, rh4, rl0, rh0, d4p0, d4p1, d4p2, d4p3, eDummy);

  step0(rl5, rh5, d0p0, d0p1, s0);
  stepW<true>(rl5, rh5, rl4, rh4, d1p0, d1p1, d1p2, d1p3, e1);
  stepW<true>(rl5, rh5, rl3, rh3, d2p0, d2p1, d2p2, d2p3, e2);
  stepW<true>(rl5, rh5, rl2, rh2, d3p0, d3p1, d3p2, d3p3, e3);
  stepW<false>(rl5, rh5, rl1, rh1, d4p0, d4p1, d4p2, d4p3, eDummy);

  step0(rl6, rh6, d0p0, d0p1, s0);
  stepW<true>(rl6, rh6, rl5, rh5, d1p0, d1p1, d1p2, d1p3, e1);
  stepW<true>(rl6, rh6, rl4, rh4, d2p0, d2p1, d2p2, d2p3, e2);
  stepW<true>(rl6, rh6, rl3, rh3, d3p0, d3p1, d3p2, d3p3, e3);
  stepW<false>(rl6, rh6, rl2, rh2, d4p0, d4p1, d4p2, d4p3, eDummy);

  step0(rl7, rh7, d0p0, d0p1, s0);
  stepW<true>(rl7, rh7, rl6, rh6, d1p0, d1p1, d1p2, d1p3, e1);
  stepW<true>(rl7, rh7, rl5, rh5, d2p0, d2p1, d2p2, d2p3, e2);
  stepW<true>(rl7, rh7, rl4, rh4, d3p0, d3p1, d3p2, d3p3, e3);
  stepW<false>(rl7, rh7, rl3, rh3, d4p0, d4p1, d4p2, d4p3, eDummy);

  const float ev1 = e1.x + e1.y;
  const float ev2 = e2.x + e2.y;
  const float ev3 = e3.x + e3.y;
  const float a4  = s0.x + s0.y;

#define LDS_ST(e4, A, B, C, Dv)                                             \
  do {                                                                      \
    f32x4 v_ = {A, B, C, Dv};                                               \
    *reinterpret_cast<f32x4*>(wbase + (((e4) ^ sw) << 2)) = v_;             \
  } while (0)

  if (valid) {
    // row 0 (oy=0, dy=-4)
    LDS_ST(0,  d4p0.x, d4p0.y, d4p1.x, d4p1.y);
    LDS_ST(1,  d4p2.x, d4p2.y, d4p3.x, d4p3.y);
    // row 1 (dy=-3) + mirror row 7
    LDS_ST(2,  d3p0.x, d3p0.y, d3p1.x, d3p1.y);
    LDS_ST(3,  d3p2.x, d3p2.y, d3p3.x, d3p3.y);
    LDS_ST(14, ev3,    d3p3.y, d3p3.x, d3p2.y);
    LDS_ST(15, d3p2.x, d3p1.y, d3p1.x, d3p0.y);
    // row 2 (dy=-2) + mirror row 6
    LDS_ST(4,  d2p0.x, d2p0.y, d2p1.x, d2p1.y);
    LDS_ST(5,  d2p2.x, d2p2.y, d2p3.x, d2p3.y);
    LDS_ST(12, ev2,    d2p3.y, d2p3.x, d2p2.y);
    LDS_ST(13, d2p2.x, d2p1.y, d2p1.x, d2p0.y);
    // row 3 (dy=-1) + mirror row 5
    LDS_ST(6,  d1p0.x, d1p0.y, d1p1.x, d1p1.y);
    LDS_ST(7,  d1p2.x, d1p2.y, d1p3.x, d1p3.y);
    LDS_ST(10, ev1,    d1p3.y, d1p3.x, d1p2.y);
    LDS_ST(11, d1p2.x, d1p1.y, d1p1.x, d1p0.y);
    // row 4 (dy=0, self-mirrored)
    LDS_ST(8,  d0p0.x, d0p0.y, d0p1.x, d0p1.y);
    LDS_ST(9,  a4,     d0p1.y, d0p1.x, d0p0.y);
  }
#undef LDS_ST

  // NO __syncthreads: each wave reads back only its OWN two LDS planes
  // (same-wave ds ordering is compiler-enforced via lgkmcnt). Each wave
  // streams its 2 output rows: 64 lanes x 16 B consecutive = full lines.
#pragma unroll
  for (int r = 0; r < 2; ++r) {
    const int hrow = hp * 2 + r;
    if (hrow >= NH) continue;  // wave-uniform (only hp=15, r=1)
    float* orun = out + (size_t)(bc * NH + hrow) * (NW * 64);
    for (int idx = lane; idx < NW * 16; idx += 64) {
      const int ww = idx >> 4;
      const int e4 = idx & 15;
      f32x4 v = *reinterpret_cast<const f32x4*>(&lds[2 * g + r][ww][(e4 ^ (ww & 7)) << 2]);
      *reinterpret_cast<f32x4*>(orun + (size_t)idx * 4) = v;
    }
  }
}

extern "C" void kernel_launch(void* const* d_in, const int* in_sizes, int n_in,
                              void* d_out, int out_size, void* d_ws, size_t ws_size,
                              hipStream_t stream) {
  const float* x = (const float*)d_in[0];
  float* out = (float*)d_out;
  // 512 bc-planes x 4 hp-quads
  lacorr2d_kernel<<<512 * 4, 256, 0, stream>>>(x, out);
}